// Round 1
// baseline (1634.442 us; speedup 1.0000x reference)
//
#include <hip/hip_runtime.h>

// Problem constants (T, B, D) = (2048, 4, 1024), fp32 everywhere.
static constexpr int T = 2048;
static constexpr int B = 4;
static constexpr int D = 1024;
static constexpr int E = 2 * D;      // 2048
static constexpr int M1 = T * B;     // 8192

static constexpr int BM = 128, BN = 128, BK = 16;
static constexpr int LP = 132;       // LDS row length (pad 128 -> 132: transpose writes = 2-way conflict = free)

// C[m,n] = alpha * sum_k A[m,k] * (TRANSB ? Bm[n,k] : Bm[k,n]) + bias[n]
// All of M, N multiples of 128 and K multiple of 16 in this problem -> no bounds checks.
template <bool TRANSB>
__global__ __launch_bounds__(256) void gemm_kernel(
    const float* __restrict__ A, const float* __restrict__ Bm,
    float* __restrict__ C, const float* __restrict__ bias,
    int K, int lda, int ldb, int ldc,
    long long aBatch, long long bBatch, long long cBatch, float alpha)
{
    __shared__ float As[BK][LP];
    __shared__ float Bs[BK][LP];

    const int bm = blockIdx.y * BM;
    const int bn = blockIdx.x * BN;
    const long long zb = blockIdx.z;
    A += zb * aBatch;
    Bm += zb * bBatch;
    C += zb * cBatch;

    const int tid = threadIdx.x;
    const int tx = tid & 15;   // column group 0..15
    const int ty = tid >> 4;   // row group 0..15

    float acc[8][8];
#pragma unroll
    for (int i = 0; i < 8; ++i)
#pragma unroll
        for (int j = 0; j < 8; ++j) acc[i][j] = 0.0f;

    const int arow = tid >> 2;         // 0..63
    const int akq = (tid & 3) << 2;    // 0,4,8,12

    for (int k0 = 0; k0 < K; k0 += BK) {
        // Stage A tile (always K-contiguous rows): LDS transpose to k-major.
#pragma unroll
        for (int s = 0; s < 2; ++s) {
            const int r = arow + s * 64;
            const float4 av = *(const float4*)(A + (long long)(bm + r) * lda + (k0 + akq));
            As[akq + 0][r] = av.x;
            As[akq + 1][r] = av.y;
            As[akq + 2][r] = av.z;
            As[akq + 3][r] = av.w;
        }
        if (TRANSB) {
#pragma unroll
            for (int s = 0; s < 2; ++s) {
                const int r = arow + s * 64;
                const float4 bv = *(const float4*)(Bm + (long long)(bn + r) * ldb + (k0 + akq));
                Bs[akq + 0][r] = bv.x;
                Bs[akq + 1][r] = bv.y;
                Bs[akq + 2][r] = bv.z;
                Bs[akq + 3][r] = bv.w;
            }
        } else {
            const int bk = tid >> 5;          // 0..7
            const int nq = (tid & 31) << 2;   // 0..124
#pragma unroll
            for (int s = 0; s < 2; ++s) {
                const int kk = bk + s * 8;
                const float4 bv = *(const float4*)(Bm + (long long)(k0 + kk) * ldb + (bn + nq));
                *(float4*)&Bs[kk][nq] = bv;
            }
        }
        __syncthreads();

#pragma unroll
        for (int kk = 0; kk < BK; ++kk) {
            const float4 a0 = *(const float4*)&As[kk][ty * 4];
            const float4 a1 = *(const float4*)&As[kk][ty * 4 + 64];
            const float4 b0 = *(const float4*)&Bs[kk][tx * 4];
            const float4 b1 = *(const float4*)&Bs[kk][tx * 4 + 64];
            const float av[8] = {a0.x, a0.y, a0.z, a0.w, a1.x, a1.y, a1.z, a1.w};
            const float bv[8] = {b0.x, b0.y, b0.z, b0.w, b1.x, b1.y, b1.z, b1.w};
#pragma unroll
            for (int i = 0; i < 8; ++i)
#pragma unroll
                for (int j = 0; j < 8; ++j) acc[i][j] += av[i] * bv[j];
        }
        __syncthreads();
    }

    float bvals[8];
#pragma unroll
    for (int j = 0; j < 8; ++j) {
        const int n = bn + tx * 4 + (j & 3) + (j >> 2) * 64;
        bvals[j] = bias ? bias[n] : 0.0f;
    }
#pragma unroll
    for (int i = 0; i < 8; ++i) {
        const int m = bm + ty * 4 + (i & 3) + (i >> 2) * 64;
        float4 o0, o1;
        o0.x = acc[i][0] * alpha + bvals[0];
        o0.y = acc[i][1] * alpha + bvals[1];
        o0.z = acc[i][2] * alpha + bvals[2];
        o0.w = acc[i][3] * alpha + bvals[3];
        o1.x = acc[i][4] * alpha + bvals[4];
        o1.y = acc[i][5] * alpha + bvals[5];
        o1.z = acc[i][6] * alpha + bvals[6];
        o1.w = acc[i][7] * alpha + bvals[7];
        *(float4*)(C + (long long)m * ldc + bn + tx * 4) = o0;
        *(float4*)(C + (long long)m * ldc + bn + tx * 4 + 64) = o1;
    }
}

// In-place softmax over rows of length T (=2048). One block (256 thr) per row.
__global__ __launch_bounds__(256) void softmax_kernel(float* __restrict__ W)
{
    const long long row = blockIdx.x;
    float* p = W + row * (long long)T;
    const int tid = threadIdx.x;

    float4 v0 = ((const float4*)p)[tid];
    float4 v1 = ((const float4*)p)[tid + 256];

    float m = fmaxf(fmaxf(fmaxf(v0.x, v0.y), fmaxf(v0.z, v0.w)),
                    fmaxf(fmaxf(v1.x, v1.y), fmaxf(v1.z, v1.w)));
#pragma unroll
    for (int off = 1; off < 64; off <<= 1) m = fmaxf(m, __shfl_xor(m, off));

    __shared__ float red[4];
    const int wid = tid >> 6, lane = tid & 63;
    if (lane == 0) red[wid] = m;
    __syncthreads();
    m = fmaxf(fmaxf(red[0], red[1]), fmaxf(red[2], red[3]));
    __syncthreads();

    v0.x = expf(v0.x - m); v0.y = expf(v0.y - m);
    v0.z = expf(v0.z - m); v0.w = expf(v0.w - m);
    v1.x = expf(v1.x - m); v1.y = expf(v1.y - m);
    v1.z = expf(v1.z - m); v1.w = expf(v1.w - m);

    float s = v0.x + v0.y + v0.z + v0.w + v1.x + v1.y + v1.z + v1.w;
#pragma unroll
    for (int off = 1; off < 64; off <<= 1) s += __shfl_xor(s, off);
    if (lane == 0) red[wid] = s;
    __syncthreads();
    s = red[0] + red[1] + red[2] + red[3];

    const float inv = 1.0f / s;
    v0.x *= inv; v0.y *= inv; v0.z *= inv; v0.w *= inv;
    v1.x *= inv; v1.y *= inv; v1.z *= inv; v1.w *= inv;

    ((float4*)p)[tid] = v0;
    ((float4*)p)[tid + 256] = v1;
}

extern "C" void kernel_launch(void* const* d_in, const int* in_sizes, int n_in,
                              void* d_out, int out_size, void* d_ws, size_t ws_size,
                              hipStream_t stream)
{
    const float* query         = (const float*)d_in[0]; // (T,B,D)
    const float* input_feature = (const float*)d_in[1]; // (T,B,D)
    const float* w_in          = (const float*)d_in[2]; // (2D,D)
    const float* b_in          = (const float*)d_in[3]; // (2D,)
    const float* w_out         = (const float*)d_in[4]; // (D,D)
    const float* b_out         = (const float*)d_in[5]; // (D,)

    float* out_attn = (float*)d_out;                       // (T,B,D)
    float* out_w    = out_attn + (long long)T * B * D;     // (B,T,T)

    float* kv       = (float*)d_ws;                        // (M1, E) = 64 MB
    float* attn_mid = kv + (long long)M1 * E;              // (M1, D) = 32 MB

    const dim3 blk(256);

    // 1) kv[m,e] = X[m,:] . Win[e,:] + b_in[e]         (m = t*B+b)
    gemm_kernel<true><<<dim3(E / BN, M1 / BM, 1), blk, 0, stream>>>(
        input_feature, w_in, kv, b_in, D, D, D, E, 0, 0, 0, 1.0f);

    // 2) logits[b,t,s] = (1/32) * q[t,b,:] . k[s,b,:]  (k = kv[...,:D]) -> into out_w
    gemm_kernel<true><<<dim3(T / BN, T / BM, B), blk, 0, stream>>>(
        query, kv, out_w, nullptr, D, B * D, E * B, T,
        (long long)D, (long long)E, (long long)T * T, 0.03125f);

    // 3) softmax over s, in-place in out_w (this IS output 1)
    softmax_kernel<<<dim3(B * T), blk, 0, stream>>>(out_w);

    // 4) attn_mid[t*B+b, d] = sum_s P[b,t,s] * v[s,b,d]   (v = kv[...,D:])
    gemm_kernel<false><<<dim3(D / BN, T / BM, B), blk, 0, stream>>>(
        out_w, kv + D, attn_mid, nullptr, T, T, E * B, B * D,
        (long long)T * T, (long long)E, (long long)D, 1.0f);

    // 5) out[m,e] = attn_mid[m,:] . Wout[e,:] + b_out[e]
    gemm_kernel<true><<<dim3(D / BN, M1 / BM, 1), blk, 0, stream>>>(
        attn_mid, w_out, out_attn, b_out, D, D, D, D, 0, 0, 0, 1.0f);
}

// Round 2
// 551.208 us; speedup vs baseline: 2.9652x; 2.9652x over previous
//
#include <hip/hip_runtime.h>
#include <hip/hip_bf16.h>
#include <type_traits>

static constexpr int T = 2048;
static constexpr int B = 4;
static constexpr int D = 1024;
static constexpr int E = 2 * D;     // 2048
static constexpr int M1 = T * B;    // 8192

typedef __attribute__((ext_vector_type(8))) short short8;   // 8 bf16 = 4 VGPRs (MFMA A/B frag)
typedef __attribute__((ext_vector_type(4))) float f32x4;    // MFMA C/D frag

__device__ inline ushort f2bf(float x) {
    __hip_bfloat16 h = __float2bfloat16(x);
    return __builtin_bit_cast(ushort, h);
}

__device__ inline void glds16(const void* g, void* l) {
    __builtin_amdgcn_global_load_lds(
        (const __attribute__((address_space(1))) void*)g,
        (__attribute__((address_space(3))) void*)l, 16, 0, 0);
}

// C[m,n] = alpha * sum_k A[m,k]*Bt[n,k] + bias[n]   (NT: both operands k-contiguous)
// AT = ushort (bf16) or float (staged fp32, converted to bf16 in-register).
// OT = float or ushort (bf16). M,N multiples of 128; K multiple of 32. ld* in elements.
template <typename AT, typename OT>
__global__ __launch_bounds__(256) void mfma_gemm_nt(
    const AT* __restrict__ A, const ushort* __restrict__ Bt,
    OT* __restrict__ C, const float* __restrict__ bias,
    int K, int lda, int ldb, int ldc,
    long long aBatch, long long bBatch, long long cBatch, float alpha)
{
    constexpr bool A_F32 = std::is_same<AT, float>::value;
    __shared__ AT As[128 * 32];       // bf16: 8KB, fp32: 16KB — rows of 32 k-elements
    __shared__ ushort Bs[128 * 32];   // 8KB

    const int tid  = threadIdx.x;
    const int lane = tid & 63;
    const int wave = tid >> 6;        // 0..3
    const int wm = (wave & 1) * 64;   // wave's M offset in tile
    const int wn = (wave >> 1) * 64;  // wave's N offset in tile

    const int bm = blockIdx.y * 128;
    const int bn = blockIdx.x * 128;
    A  += blockIdx.z * aBatch;
    Bt += blockIdx.z * bBatch;
    C  += blockIdx.z * cBatch;

    f32x4 acc[4][4] = {};

    // bf16 staging: lane covers LDS byte lane*16 within 1KB region -> row = base + lane/4, chunk=(lane&3)*8 bf16
    const int brow   = wave * 32 + (lane >> 2);
    const int bchunk = (lane & 3) * 8;
    // fp32 staging: 1KB region covers 8 rows of 128B -> row = base + lane/8, chunk=(lane&7)*4 floats
    const int arow32   = wave * 32 + (lane >> 3);
    const int achunk32 = (lane & 7) * 4;

    for (int k0 = 0; k0 < K; k0 += 32) {
        __syncthreads();   // previous tile's ds_reads done before overwrite
        // stage B tile: 128 rows x 64B, 2 wave-instrs of 1KB each
#pragma unroll
        for (int j = 0; j < 2; ++j) {
            const ushort* g = Bt + (long long)(bn + brow + j * 16) * ldb + (k0 + bchunk);
            glds16(g, (void*)&Bs[wave * 1024 + j * 512]);
        }
        if constexpr (!A_F32) {
#pragma unroll
            for (int j = 0; j < 2; ++j) {
                const AT* g = A + (long long)(bm + brow + j * 16) * lda + (k0 + bchunk);
                glds16(g, (void*)&As[wave * 1024 + j * 512]);
            }
        } else {
#pragma unroll
            for (int j = 0; j < 4; ++j) {
                const float* g = (const float*)A + (long long)(bm + arow32 + j * 8) * lda + (k0 + achunk32);
                glds16(g, (void*)&As[wave * 1024 + j * 256]);
            }
        }
        __syncthreads();   // compiler emits vmcnt(0) drain for global_load_lds

        short8 af[4], bf[4];
#pragma unroll
        for (int i = 0; i < 4; ++i) {
            const int m = wm + i * 16 + (lane & 15);
            if constexpr (!A_F32) {
                af[i] = *(const short8*)&As[m * 32 + (lane >> 4) * 8];
            } else {
                const float* p = (const float*)&As[m * 32 + (lane >> 4) * 8];
                const float4 f0 = *(const float4*)p;
                const float4 f1 = *(const float4*)(p + 4);
                short8 r;
                r[0] = (short)f2bf(f0.x); r[1] = (short)f2bf(f0.y);
                r[2] = (short)f2bf(f0.z); r[3] = (short)f2bf(f0.w);
                r[4] = (short)f2bf(f1.x); r[5] = (short)f2bf(f1.y);
                r[6] = (short)f2bf(f1.z); r[7] = (short)f2bf(f1.w);
                af[i] = r;
            }
        }
#pragma unroll
        for (int j = 0; j < 4; ++j) {
            const int n = wn + j * 16 + (lane & 15);
            bf[j] = *(const short8*)&Bs[n * 32 + (lane >> 4) * 8];
        }
#pragma unroll
        for (int i = 0; i < 4; ++i)
#pragma unroll
            for (int j = 0; j < 4; ++j)
                acc[i][j] = __builtin_amdgcn_mfma_f32_16x16x32_bf16(af[i], bf[j], acc[i][j], 0, 0, 0);
    }

    // epilogue: C/D layout col=lane&15, row=(lane>>4)*4+r  [verified m89]
#pragma unroll
    for (int j = 0; j < 4; ++j) {
        const int col = bn + wn + j * 16 + (lane & 15);
        const float bv = bias ? bias[col] : 0.0f;
#pragma unroll
        for (int i = 0; i < 4; ++i) {
            const int row0 = bm + wm + i * 16 + ((lane >> 4) << 2);
#pragma unroll
            for (int r = 0; r < 4; ++r) {
                const float v = acc[i][j][r] * alpha + bv;
                if constexpr (std::is_same<OT, float>::value)
                    C[(long long)(row0 + r) * ldc + col] = v;
                else
                    C[(long long)(row0 + r) * ldc + col] = f2bf(v);
            }
        }
    }
}

// fp32 -> bf16 cast, one float4 per thread, exact sizes (n % 1024 == 0)
__global__ __launch_bounds__(256) void cast_bf16(const float* __restrict__ in,
                                                 ushort* __restrict__ out, int n4)
{
    const int i = blockIdx.x * 256 + threadIdx.x;
    if (i >= n4) return;
    const float4 v = ((const float4*)in)[i];
    ushort4 o;
    o.x = f2bf(v.x); o.y = f2bf(v.y); o.z = f2bf(v.z); o.w = f2bf(v.w);
    ((ushort4*)out)[i] = o;
}

// vt[b][d][s] = kv[(s*B+b)*E + D + d]   (64x64 LDS tile transpose per block)
__global__ __launch_bounds__(256) void transpose_v(const ushort* __restrict__ kv,
                                                   ushort* __restrict__ vt)
{
    __shared__ ushort tile[64][65];
    const int s0 = blockIdx.x * 64, d0 = blockIdx.y * 64, b = blockIdx.z;
    const int t = threadIdx.x;
    const int dl = (t & 15) * 4, sl = t >> 4;
#pragma unroll
    for (int p = 0; p < 4; ++p) {
        const int s = sl + p * 16;
        const ushort4 v = *(const ushort4*)&kv[((long long)(s0 + s) * B + b) * E + D + d0 + dl];
        tile[s][dl + 0] = v.x; tile[s][dl + 1] = v.y;
        tile[s][dl + 2] = v.z; tile[s][dl + 3] = v.w;
    }
    __syncthreads();
    const int dl2 = t >> 4, sl2 = (t & 15) * 4;
#pragma unroll
    for (int p = 0; p < 4; ++p) {
        const int d = dl2 + p * 16;
        ushort4 o;
        o.x = tile[sl2 + 0][d]; o.y = tile[sl2 + 1][d];
        o.z = tile[sl2 + 2][d]; o.w = tile[sl2 + 3][d];
        *(ushort4*)&vt[(long long)b * D * T + (long long)(d0 + d) * T + s0 + sl2] = o;
    }
}

// in-place fp32 softmax over rows of length T=2048, one 256-thr block per row
__global__ __launch_bounds__(256) void softmax_kernel(float* __restrict__ W)
{
    const long long row = blockIdx.x;
    float* p = W + row * (long long)T;
    const int tid = threadIdx.x;

    float4 v0 = ((const float4*)p)[tid];
    float4 v1 = ((const float4*)p)[tid + 256];

    float m = fmaxf(fmaxf(fmaxf(v0.x, v0.y), fmaxf(v0.z, v0.w)),
                    fmaxf(fmaxf(v1.x, v1.y), fmaxf(v1.z, v1.w)));
#pragma unroll
    for (int off = 1; off < 64; off <<= 1) m = fmaxf(m, __shfl_xor(m, off));

    __shared__ float red[4];
    const int wid = tid >> 6, lane = tid & 63;
    if (lane == 0) red[wid] = m;
    __syncthreads();
    m = fmaxf(fmaxf(red[0], red[1]), fmaxf(red[2], red[3]));
    __syncthreads();

    v0.x = expf(v0.x - m); v0.y = expf(v0.y - m);
    v0.z = expf(v0.z - m); v0.w = expf(v0.w - m);
    v1.x = expf(v1.x - m); v1.y = expf(v1.y - m);
    v1.z = expf(v1.z - m); v1.w = expf(v1.w - m);

    float s = v0.x + v0.y + v0.z + v0.w + v1.x + v1.y + v1.z + v1.w;
#pragma unroll
    for (int off = 1; off < 64; off <<= 1) s += __shfl_xor(s, off);
    if (lane == 0) red[wid] = s;
    __syncthreads();
    s = red[0] + red[1] + red[2] + red[3];

    const float inv = 1.0f / s;
    v0.x *= inv; v0.y *= inv; v0.z *= inv; v0.w *= inv;
    v1.x *= inv; v1.y *= inv; v1.z *= inv; v1.w *= inv;

    ((float4*)p)[tid] = v0;
    ((float4*)p)[tid + 256] = v1;
}

extern "C" void kernel_launch(void* const* d_in, const int* in_sizes, int n_in,
                              void* d_out, int out_size, void* d_ws, size_t ws_size,
                              hipStream_t stream)
{
    const float* query = (const float*)d_in[0];   // (T,B,D)
    const float* x     = (const float*)d_in[1];   // (T,B,D)
    const float* w_in  = (const float*)d_in[2];   // (2D,D)
    const float* b_in  = (const float*)d_in[3];   // (2D,)
    const float* w_out = (const float*)d_in[4];   // (D,D)
    const float* b_out = (const float*)d_in[5];   // (D,)

    float* out_attn = (float*)d_out;                      // (T,B,D) fp32
    float* out_w    = out_attn + (long long)T * B * D;    // (B,T,T) fp32

    // workspace layout (86 MB total; 96 MB proven available in R1):
    char* ws = (char*)d_ws;
    ushort* qbf  = (ushort*)(ws);                          // 16 MB, dead after QK
    ushort* xbf  = (ushort*)(ws + (16ll << 20));           // 16 MB, dead after GEMM1
    ushort* wibf = (ushort*)(ws + (32ll << 20));           // 4 MB
    ushort* wobf = (ushort*)(ws + (36ll << 20));           // 2 MB
    ushort* kv   = (ushort*)(ws + (38ll << 20));           // 32 MB (s,b,2D) bf16
    ushort* vt   = (ushort*)(ws + (70ll << 20));           // 16 MB (b,d,s) bf16
    ushort* amid = xbf;                                    // 16 MB reuse (t,b,d) bf16

    // casts
    cast_bf16<<<dim3(8192), 256, 0, stream>>>(x, xbf, (T * B * D) / 4);
    cast_bf16<<<dim3(2048), 256, 0, stream>>>(w_in, wibf, (E * D) / 4);
    cast_bf16<<<dim3(8192), 256, 0, stream>>>(query, qbf, (T * B * D) / 4);
    cast_bf16<<<dim3(1024), 256, 0, stream>>>(w_out, wobf, (D * D) / 4);

    // 1) kv = X . Win^T + b_in       M=8192 N=2048 K=1024
    mfma_gemm_nt<ushort, ushort><<<dim3(E / 128, M1 / 128, 1), 256, 0, stream>>>(
        xbf, wibf, kv, b_in, D, D, D, E, 0, 0, 0, 1.0f);

    // 2) vt = transpose of V half
    transpose_v<<<dim3(T / 64, D / 64, B), 256, 0, stream>>>(kv, vt);

    // 3) logits[b,t,s] = (1/32) q . k   M=2048 N=2048 K=1024, batch B
    mfma_gemm_nt<ushort, float><<<dim3(T / 128, T / 128, B), 256, 0, stream>>>(
        qbf, kv, out_w, nullptr, D, B * D, B * E, T,
        (long long)D, (long long)E, (long long)T * T, 0.03125f);

    // 4) softmax rows (in place; this IS output 1)
    softmax_kernel<<<dim3(B * T), 256, 0, stream>>>(out_w);

    // 5) amid[t,b,d] = P . vt^T      M=2048 N=1024 K=2048, batch B (A is fp32 P)
    mfma_gemm_nt<float, ushort><<<dim3(D / 128, T / 128, B), 256, 0, stream>>>(
        out_w, vt, amid, nullptr, T, T, T, B * D,
        (long long)T * T, (long long)D * T, (long long)D, 1.0f);

    // 6) out = amid . Wout^T + b_out  M=8192 N=1024 K=1024
    mfma_gemm_nt<ushort, float><<<dim3(D / 128, M1 / 128, 1), 256, 0, stream>>>(
        amid, wobf, out_attn, b_out, D, D, D, D, 0, 0, 0, 1.0f);
}

// Round 3
// 406.353 us; speedup vs baseline: 4.0222x; 1.3565x over previous
//
#include <hip/hip_runtime.h>
#include <hip/hip_bf16.h>
#include <type_traits>

static constexpr int T = 2048;
static constexpr int B = 4;
static constexpr int D = 1024;
static constexpr int E = 2 * D;     // 2048
static constexpr int M1 = T * B;    // 8192

typedef __attribute__((ext_vector_type(8))) short short8;   // 8 bf16 = 4 VGPRs (MFMA A/B frag)
typedef __attribute__((ext_vector_type(4))) float f32x4;    // MFMA C/D frag

__device__ inline ushort f2bf(float x) {
    __hip_bfloat16 h = __float2bfloat16(x);
    return __builtin_bit_cast(ushort, h);
}

__device__ inline void glds16(const void* g, void* l) {
    __builtin_amdgcn_global_load_lds(
        (const __attribute__((address_space(1))) void*)g,
        (__attribute__((address_space(3))) void*)l, 16, 0, 0);
}

// C[m,n] = alpha * sum_k A[m,k]*Bt[n,k] + bias[n]   (NT, bf16 operands).
// LDS tiles use an XOR chunk swizzle: global 16B-chunk c of tile-row m lives at
// LDS chunk c ^ ((m>>1)&3). Makes both the glds16 staging AND the ds_read_b128
// fragment reads 2-way-per-bank (free) instead of 8/16-way conflicted.
template <typename OT>
__global__ __launch_bounds__(256) void mfma_gemm_nt(
    const ushort* __restrict__ A, const ushort* __restrict__ Bt,
    OT* __restrict__ C, const float* __restrict__ bias,
    int K, int lda, int ldb, int ldc,
    long long aBatch, long long bBatch, long long cBatch, float alpha)
{
    __shared__ ushort As[128 * 32];   // 8KB: 128 rows x 32 bf16 (4 chunks of 8)
    __shared__ ushort Bs[128 * 32];   // 8KB

    const int tid  = threadIdx.x;
    const int lane = tid & 63;
    const int wave = tid >> 6;        // 0..3
    const int wm = (wave & 1) * 64;
    const int wn = (wave >> 1) * 64;

    const int bm = blockIdx.y * 128;
    const int bn = blockIdx.x * 128;
    A  += blockIdx.z * aBatch;
    Bt += blockIdx.z * bBatch;
    C  += blockIdx.z * cBatch;

    f32x4 acc[4][4] = {};

    // staging: lane L writes LDS slot (row base+ (L>>2), chunk L&3); that slot
    // holds global chunk (L&3) ^ s(m). s(m)=(m>>1)&3 reduces to (L>>3)&3.
    const int srow = lane >> 2;                                  // 0..15
    const int sElem = (((lane & 3) ^ ((lane >> 3) & 3))) * 8;    // swizzled global elem offset
    // fragment read: chunk (lane>>4) ^ s(m), s(m) reduces to (lane>>1)&3.
    const int rElem = ((lane >> 4) ^ ((lane >> 1) & 3)) * 8;

    for (int k0 = 0; k0 < K; k0 += 32) {
        __syncthreads();
#pragma unroll
        for (int j = 0; j < 2; ++j) {
            const int r = wave * 32 + j * 16 + srow;   // tile row
            glds16(Bt + (long long)(bn + r) * ldb + (k0 + sElem),
                   (void*)&Bs[wave * 1024 + j * 512]);
            glds16(A + (long long)(bm + r) * lda + (k0 + sElem),
                   (void*)&As[wave * 1024 + j * 512]);
        }
        __syncthreads();

        short8 af[4], bf[4];
#pragma unroll
        for (int i = 0; i < 4; ++i) {
            const int m = wm + i * 16 + (lane & 15);
            af[i] = *(const short8*)&As[m * 32 + rElem];
        }
#pragma unroll
        for (int j = 0; j < 4; ++j) {
            const int n = wn + j * 16 + (lane & 15);
            bf[j] = *(const short8*)&Bs[n * 32 + rElem];
        }
#pragma unroll
        for (int i = 0; i < 4; ++i)
#pragma unroll
            for (int j = 0; j < 4; ++j)
                acc[i][j] = __builtin_amdgcn_mfma_f32_16x16x32_bf16(af[i], bf[j], acc[i][j], 0, 0, 0);
    }

    // epilogue: C/D layout col=lane&15, row=(lane>>4)*4+r  [verified m89]
#pragma unroll
    for (int j = 0; j < 4; ++j) {
        const int col = bn + wn + j * 16 + (lane & 15);
        const float bv = bias ? bias[col] : 0.0f;
#pragma unroll
        for (int i = 0; i < 4; ++i) {
            const int row0 = bm + wm + i * 16 + ((lane >> 4) << 2);
#pragma unroll
            for (int r = 0; r < 4; ++r) {
                const float v = acc[i][j][r] * alpha + bv;
                if constexpr (std::is_same<OT, float>::value)
                    C[(long long)(row0 + r) * ldc + col] = v;
                else
                    C[(long long)(row0 + r) * ldc + col] = f2bf(v);
            }
        }
    }
}

// fp32 -> bf16 cast, one float4 per thread
__global__ __launch_bounds__(256) void cast_bf16(const float* __restrict__ in,
                                                 ushort* __restrict__ out, int n4)
{
    const int i = blockIdx.x * 256 + threadIdx.x;
    if (i >= n4) return;
    const float4 v = ((const float4*)in)[i];
    ushort4 o;
    o.x = f2bf(v.x); o.y = f2bf(v.y); o.z = f2bf(v.z); o.w = f2bf(v.w);
    ((ushort4*)out)[i] = o;
}

// vt[b][d][s] = kv[(s*B+b)*E + D + d]   (64x64 LDS tile transpose per block)
__global__ __launch_bounds__(256) void transpose_v(const ushort* __restrict__ kv,
                                                   ushort* __restrict__ vt)
{
    __shared__ ushort tile[64][65];
    const int s0 = blockIdx.x * 64, d0 = blockIdx.y * 64, b = blockIdx.z;
    const int t = threadIdx.x;
    const int dl = (t & 15) * 4, sl = t >> 4;
#pragma unroll
    for (int p = 0; p < 4; ++p) {
        const int s = sl + p * 16;
        const ushort4 v = *(const ushort4*)&kv[((long long)(s0 + s) * B + b) * E + D + d0 + dl];
        tile[s][dl + 0] = v.x; tile[s][dl + 1] = v.y;
        tile[s][dl + 2] = v.z; tile[s][dl + 3] = v.w;
    }
    __syncthreads();
    const int dl2 = t >> 4, sl2 = (t & 15) * 4;
#pragma unroll
    for (int p = 0; p < 4; ++p) {
        const int d = dl2 + p * 16;
        ushort4 o;
        o.x = tile[sl2 + 0][d]; o.y = tile[sl2 + 1][d];
        o.z = tile[sl2 + 2][d]; o.w = tile[sl2 + 3][d];
        *(ushort4*)&vt[(long long)b * D * T + (long long)(d0 + d) * T + s0 + sl2] = o;
    }
}

// in-place fp32 softmax over rows of length T=2048, one 256-thr block per row.
// Also emits a bf16 copy of the row into Pbf (same (B,T,T) layout) for the PV GEMM.
__global__ __launch_bounds__(256) void softmax_kernel(float* __restrict__ W,
                                                      ushort* __restrict__ Pbf)
{
    const long long row = blockIdx.x;
    float* p = W + row * (long long)T;
    ushort* pb = Pbf + row * (long long)T;
    const int tid = threadIdx.x;

    float4 v0 = ((const float4*)p)[tid];
    float4 v1 = ((const float4*)p)[tid + 256];

    float m = fmaxf(fmaxf(fmaxf(v0.x, v0.y), fmaxf(v0.z, v0.w)),
                    fmaxf(fmaxf(v1.x, v1.y), fmaxf(v1.z, v1.w)));
#pragma unroll
    for (int off = 1; off < 64; off <<= 1) m = fmaxf(m, __shfl_xor(m, off));

    __shared__ float red[4];
    const int wid = tid >> 6, lane = tid & 63;
    if (lane == 0) red[wid] = m;
    __syncthreads();
    m = fmaxf(fmaxf(red[0], red[1]), fmaxf(red[2], red[3]));
    __syncthreads();

    v0.x = expf(v0.x - m); v0.y = expf(v0.y - m);
    v0.z = expf(v0.z - m); v0.w = expf(v0.w - m);
    v1.x = expf(v1.x - m); v1.y = expf(v1.y - m);
    v1.z = expf(v1.z - m); v1.w = expf(v1.w - m);

    float s = v0.x + v0.y + v0.z + v0.w + v1.x + v1.y + v1.z + v1.w;
#pragma unroll
    for (int off = 1; off < 64; off <<= 1) s += __shfl_xor(s, off);
    if (lane == 0) red[wid] = s;
    __syncthreads();
    s = red[0] + red[1] + red[2] + red[3];

    const float inv = 1.0f / s;
    v0.x *= inv; v0.y *= inv; v0.z *= inv; v0.w *= inv;
    v1.x *= inv; v1.y *= inv; v1.z *= inv; v1.w *= inv;

    ((float4*)p)[tid] = v0;
    ((float4*)p)[tid + 256] = v1;

    ushort4 o0, o1;
    o0.x = f2bf(v0.x); o0.y = f2bf(v0.y); o0.z = f2bf(v0.z); o0.w = f2bf(v0.w);
    o1.x = f2bf(v1.x); o1.y = f2bf(v1.y); o1.z = f2bf(v1.z); o1.w = f2bf(v1.w);
    ((ushort4*)pb)[tid] = o0;
    ((ushort4*)pb)[tid + 256] = o1;
}

extern "C" void kernel_launch(void* const* d_in, const int* in_sizes, int n_in,
                              void* d_out, int out_size, void* d_ws, size_t ws_size,
                              hipStream_t stream)
{
    const float* query = (const float*)d_in[0];   // (T,B,D)
    const float* x     = (const float*)d_in[1];   // (T,B,D)
    const float* w_in  = (const float*)d_in[2];   // (2D,D)
    const float* b_in  = (const float*)d_in[3];   // (2D,)
    const float* w_out = (const float*)d_in[4];   // (D,D)
    const float* b_out = (const float*)d_in[5];   // (D,)

    float* out_attn = (float*)d_out;                      // (T,B,D) fp32
    float* out_w    = out_attn + (long long)T * B * D;    // (B,T,T) fp32

    // workspace (peak 86 MB; 96 MB proven in R1):
    //  [0,16)   xbf (cast->GEMM1)         then amid (PV->out_proj)
    //  [16,32)  qbf (cast->QK)
    //  [32,36)  wibf   [36,38) wobf
    //  [38,70)  kv (GEMM1->QK/transpose)  then Pbf (softmax->PV)
    //  [70,86)  vt (transpose->PV)
    char* ws = (char*)d_ws;
    ushort* xbf  = (ushort*)(ws);
    ushort* amid = (ushort*)(ws);
    ushort* qbf  = (ushort*)(ws + (16ll << 20));
    ushort* wibf = (ushort*)(ws + (32ll << 20));
    ushort* wobf = (ushort*)(ws + (36ll << 20));
    ushort* kv   = (ushort*)(ws + (38ll << 20));
    ushort* Pbf  = (ushort*)(ws + (38ll << 20));
    ushort* vt   = (ushort*)(ws + (70ll << 20));

    cast_bf16<<<dim3(8192), 256, 0, stream>>>(x, xbf, (T * B * D) / 4);
    cast_bf16<<<dim3(2048), 256, 0, stream>>>(w_in, wibf, (E * D) / 4);
    cast_bf16<<<dim3(8192), 256, 0, stream>>>(query, qbf, (T * B * D) / 4);
    cast_bf16<<<dim3(1024), 256, 0, stream>>>(w_out, wobf, (D * D) / 4);

    // 1) kv = X . Win^T + b_in       M=8192 N=2048 K=1024
    mfma_gemm_nt<ushort><<<dim3(E / 128, M1 / 128, 1), 256, 0, stream>>>(
        xbf, wibf, kv, b_in, D, D, D, E, 0, 0, 0, 1.0f);

    // 2) vt = transpose of V half
    transpose_v<<<dim3(T / 64, D / 64, B), 256, 0, stream>>>(kv, vt);

    // 3) logits[b,t,s] = (1/32) q . k   M=2048 N=2048 K=1024, batch B
    mfma_gemm_nt<float><<<dim3(T / 128, T / 128, B), 256, 0, stream>>>(
        qbf, kv, out_w, nullptr, D, B * D, B * E, T,
        (long long)D, (long long)E, (long long)T * T, 0.03125f);

    // 4) softmax rows in-place (output 1) + bf16 copy into Pbf
    softmax_kernel<<<dim3(B * T), 256, 0, stream>>>(out_w, Pbf);

    // 5) amid[t,b,d] = P . vt^T      M=2048 N=1024 K=2048, batch B (bf16 A now)
    mfma_gemm_nt<ushort><<<dim3(D / 128, T / 128, B), 256, 0, stream>>>(
        Pbf, vt, amid, nullptr, T, T, T, B * D,
        (long long)T * T, (long long)D * T, (long long)D, 1.0f);

    // 6) out = amid . Wout^T + b_out  M=8192 N=1024 K=1024
    mfma_gemm_nt<float><<<dim3(D / 128, M1 / 128, 1), 256, 0, stream>>>(
        amid, wobf, out_attn, b_out, D, D, D, D, 0, 0, 0, 1.0f);
}

// Round 4
// 357.894 us; speedup vs baseline: 4.5668x; 1.1354x over previous
//
#include <hip/hip_runtime.h>
#include <hip/hip_bf16.h>
#include <type_traits>

static constexpr int T = 2048;
static constexpr int B = 4;
static constexpr int D = 1024;
static constexpr int E = 2 * D;     // 2048
static constexpr int M1 = T * B;    // 8192

typedef __attribute__((ext_vector_type(8))) short short8;   // 8 bf16 = 4 VGPRs (MFMA A/B frag)
typedef __attribute__((ext_vector_type(4))) float f32x4;    // MFMA C/D frag

__device__ inline ushort f2bf(float x) {
    __hip_bfloat16 h = __float2bfloat16(x);
    return __builtin_bit_cast(ushort, h);
}

__device__ inline void glds16(const void* g, void* l) {
    __builtin_amdgcn_global_load_lds(
        (const __attribute__((address_space(1))) void*)g,
        (__attribute__((address_space(3))) void*)l, 16, 0, 0);
}

// C[m,n] = alpha * sum_k A[m,k]*Bt[n,k] + bias[n]   (NT, bf16 operands), BK=64.
// LDS rows are 64 bf16 = 128B = exactly 32 banks, so row starts all alias bank 0.
// XOR chunk swizzle: global 16B-chunk c of tile-row m lives at LDS chunk c ^ (m&7).
// Staging (glds16, lane L -> row L>>3, chunk L&7): global chunk = (L&7)^(L>>3).
// Fragment read (row m=…+(lane&15), chunk kb*4+(lane>>4)): LDS chunk ^ (lane&7);
// lanes 0-7 then cover all 32 banks exactly once -> 2-way per wave = free.
template <typename OT>
__global__ __launch_bounds__(256) void mfma_gemm_nt(
    const ushort* __restrict__ A, const ushort* __restrict__ Bt,
    OT* __restrict__ C, const float* __restrict__ bias,
    int K, int lda, int ldb, int ldc,
    long long aBatch, long long bBatch, long long cBatch, float alpha)
{
    __shared__ ushort As[128 * 64];   // 16KB
    __shared__ ushort Bs[128 * 64];   // 16KB

    const int tid  = threadIdx.x;
    const int lane = tid & 63;
    const int wave = tid >> 6;        // 0..3
    const int wm = (wave & 1) * 64;
    const int wn = (wave >> 1) * 64;

    const int bm = blockIdx.y * 128;
    const int bn = blockIdx.x * 128;
    A  += blockIdx.z * aBatch;
    Bt += blockIdx.z * bBatch;
    C  += blockIdx.z * cBatch;

    f32x4 acc[4][4] = {};

    const int srow  = lane >> 3;                         // 0..7 within 8-row gang
    const int sElem = (((lane & 7) ^ (lane >> 3))) * 8;  // swizzled global elem offset
    const int rbase = ((lane >> 4) ^ (lane & 7)) * 8;    // kb=0 read chunk
    const int rxor4 = 4 * 8;                             // kb=1 flips bit2 of chunk

    for (int k0 = 0; k0 < K; k0 += 64) {
        __syncthreads();
#pragma unroll
        for (int j = 0; j < 4; ++j) {
            const int r = wave * 32 + j * 8;             // gang base row
            glds16(Bt + (long long)(bn + r + srow) * ldb + (k0 + sElem),
                   (void*)&Bs[r * 64]);
            glds16(A + (long long)(bm + r + srow) * lda + (k0 + sElem),
                   (void*)&As[r * 64]);
        }
        __syncthreads();

#pragma unroll
        for (int kb = 0; kb < 2; ++kb) {
            const int rElem = rbase ^ (kb ? rxor4 : 0);
            short8 af[4], bf[4];
#pragma unroll
            for (int i = 0; i < 4; ++i) {
                const int m = wm + i * 16 + (lane & 15);
                af[i] = *(const short8*)&As[m * 64 + rElem];
            }
#pragma unroll
            for (int j = 0; j < 4; ++j) {
                const int n = wn + j * 16 + (lane & 15);
                bf[j] = *(const short8*)&Bs[n * 64 + rElem];
            }
#pragma unroll
            for (int i = 0; i < 4; ++i)
#pragma unroll
                for (int j = 0; j < 4; ++j)
                    acc[i][j] = __builtin_amdgcn_mfma_f32_16x16x32_bf16(af[i], bf[j], acc[i][j], 0, 0, 0);
        }
    }

    // epilogue: C/D layout col=lane&15, row=(lane>>4)*4+r  [verified m89]
#pragma unroll
    for (int j = 0; j < 4; ++j) {
        const int col = bn + wn + j * 16 + (lane & 15);
        const float bv = bias ? bias[col] : 0.0f;
#pragma unroll
        for (int i = 0; i < 4; ++i) {
            const int row0 = bm + wm + i * 16 + ((lane >> 4) << 2);
#pragma unroll
            for (int r = 0; r < 4; ++r) {
                const float v = acc[i][j][r] * alpha + bv;
                if constexpr (std::is_same<OT, float>::value)
                    C[(long long)(row0 + r) * ldc + col] = v;
                else
                    C[(long long)(row0 + r) * ldc + col] = f2bf(v);
            }
        }
    }
}

// all four fp32->bf16 casts in one launch (region select by block index)
__global__ __launch_bounds__(256) void cast_all(
    const float* __restrict__ s0, ushort* __restrict__ d0, int n0,   // blocks [0, n0)
    const float* __restrict__ s1, ushort* __restrict__ d1, int n1,
    const float* __restrict__ s2, ushort* __restrict__ d2, int n2,
    const float* __restrict__ s3, ushort* __restrict__ d3, int n3)
{
    int blk = blockIdx.x;
    const float* s; ushort* d;
    if (blk < n0) { s = s0; d = d0; }
    else if ((blk -= n0) < n1) { s = s1; d = d1; }
    else if ((blk -= n1) < n2) { s = s2; d = d2; }
    else { blk -= n2; s = s3; d = d3; }
    const int i = blk * 256 + threadIdx.x;
    const float4 v = ((const float4*)s)[i];
    ushort4 o;
    o.x = f2bf(v.x); o.y = f2bf(v.y); o.z = f2bf(v.z); o.w = f2bf(v.w);
    ((ushort4*)d)[i] = o;
}

// vt[b][d][s] = kv[(s*B+b)*E + D + d]   (64x64 LDS tile transpose per block)
__global__ __launch_bounds__(256) void transpose_v(const ushort* __restrict__ kv,
                                                   ushort* __restrict__ vt)
{
    __shared__ ushort tile[64][65];
    const int s0 = blockIdx.x * 64, d0 = blockIdx.y * 64, b = blockIdx.z;
    const int t = threadIdx.x;
    const int dl = (t & 15) * 4, sl = t >> 4;
#pragma unroll
    for (int p = 0; p < 4; ++p) {
        const int s = sl + p * 16;
        const ushort4 v = *(const ushort4*)&kv[((long long)(s0 + s) * B + b) * E + D + d0 + dl];
        tile[s][dl + 0] = v.x; tile[s][dl + 1] = v.y;
        tile[s][dl + 2] = v.z; tile[s][dl + 3] = v.w;
    }
    __syncthreads();
    const int dl2 = t >> 4, sl2 = (t & 15) * 4;
#pragma unroll
    for (int p = 0; p < 4; ++p) {
        const int d = dl2 + p * 16;
        ushort4 o;
        o.x = tile[sl2 + 0][d]; o.y = tile[sl2 + 1][d];
        o.z = tile[sl2 + 2][d]; o.w = tile[sl2 + 3][d];
        *(ushort4*)&vt[(long long)b * D * T + (long long)(d0 + d) * T + s0 + sl2] = o;
    }
}

// in-place fp32 softmax over rows of length T=2048, one 256-thr block per row.
// Also emits a bf16 copy of the row into Pbf for the PV GEMM.
__global__ __launch_bounds__(256) void softmax_kernel(float* __restrict__ W,
                                                      ushort* __restrict__ Pbf)
{
    const long long row = blockIdx.x;
    float* p = W + row * (long long)T;
    ushort* pb = Pbf + row * (long long)T;
    const int tid = threadIdx.x;

    float4 v0 = ((const float4*)p)[tid];
    float4 v1 = ((const float4*)p)[tid + 256];

    float m = fmaxf(fmaxf(fmaxf(v0.x, v0.y), fmaxf(v0.z, v0.w)),
                    fmaxf(fmaxf(v1.x, v1.y), fmaxf(v1.z, v1.w)));
#pragma unroll
    for (int off = 1; off < 64; off <<= 1) m = fmaxf(m, __shfl_xor(m, off));

    __shared__ float red[4];
    const int wid = tid >> 6, lane = tid & 63;
    if (lane == 0) red[wid] = m;
    __syncthreads();
    m = fmaxf(fmaxf(red[0], red[1]), fmaxf(red[2], red[3]));
    __syncthreads();

    v0.x = expf(v0.x - m); v0.y = expf(v0.y - m);
    v0.z = expf(v0.z - m); v0.w = expf(v0.w - m);
    v1.x = expf(v1.x - m); v1.y = expf(v1.y - m);
    v1.z = expf(v1.z - m); v1.w = expf(v1.w - m);

    float s = v0.x + v0.y + v0.z + v0.w + v1.x + v1.y + v1.z + v1.w;
#pragma unroll
    for (int off = 1; off < 64; off <<= 1) s += __shfl_xor(s, off);
    if (lane == 0) red[wid] = s;
    __syncthreads();
    s = red[0] + red[1] + red[2] + red[3];

    const float inv = 1.0f / s;
    v0.x *= inv; v0.y *= inv; v0.z *= inv; v0.w *= inv;
    v1.x *= inv; v1.y *= inv; v1.z *= inv; v1.w *= inv;

    ((float4*)p)[tid] = v0;
    ((float4*)p)[tid + 256] = v1;

    ushort4 o0, o1;
    o0.x = f2bf(v0.x); o0.y = f2bf(v0.y); o0.z = f2bf(v0.z); o0.w = f2bf(v0.w);
    o1.x = f2bf(v1.x); o1.y = f2bf(v1.y); o1.z = f2bf(v1.z); o1.w = f2bf(v1.w);
    ((ushort4*)pb)[tid] = o0;
    ((ushort4*)pb)[tid + 256] = o1;
}

extern "C" void kernel_launch(void* const* d_in, const int* in_sizes, int n_in,
                              void* d_out, int out_size, void* d_ws, size_t ws_size,
                              hipStream_t stream)
{
    const float* query = (const float*)d_in[0];   // (T,B,D)
    const float* x     = (const float*)d_in[1];   // (T,B,D)
    const float* w_in  = (const float*)d_in[2];   // (2D,D)
    const float* b_in  = (const float*)d_in[3];   // (2D,)
    const float* w_out = (const float*)d_in[4];   // (D,D)
    const float* b_out = (const float*)d_in[5];   // (D,)

    float* out_attn = (float*)d_out;                      // (T,B,D) fp32
    float* out_w    = out_attn + (long long)T * B * D;    // (B,T,T) fp32

    // workspace (peak 86 MB; 96 MB proven in R1):
    //  [0,16)   xbf (cast->GEMM1)         then amid (PV->out_proj)
    //  [16,32)  qbf (cast->QK)
    //  [32,36)  wibf   [36,38) wobf
    //  [38,70)  kv (GEMM1->QK/transpose)  then Pbf (softmax->PV)
    //  [70,86)  vt (transpose->PV)
    char* ws = (char*)d_ws;
    ushort* xbf  = (ushort*)(ws);
    ushort* amid = (ushort*)(ws);
    ushort* qbf  = (ushort*)(ws + (16ll << 20));
    ushort* wibf = (ushort*)(ws + (32ll << 20));
    ushort* wobf = (ushort*)(ws + (36ll << 20));
    ushort* kv   = (ushort*)(ws + (38ll << 20));
    ushort* Pbf  = (ushort*)(ws + (38ll << 20));
    ushort* vt   = (ushort*)(ws + (70ll << 20));

    // one cast launch for x, w_in, q, w_out (block counts: n4/256 each)
    cast_all<<<dim3(8192 + 2048 + 8192 + 1024), 256, 0, stream>>>(
        x, xbf, 8192, w_in, wibf, 2048, query, qbf, 8192, w_out, wobf, 1024);

    // 1) kv = X . Win^T + b_in       M=8192 N=2048 K=1024
    mfma_gemm_nt<ushort><<<dim3(E / 128, M1 / 128, 1), 256, 0, stream>>>(
        xbf, wibf, kv, b_in, D, D, D, E, 0, 0, 0, 1.0f);

    // 2) vt = transpose of V half
    transpose_v<<<dim3(T / 64, D / 64, B), 256, 0, stream>>>(kv, vt);

    // 3) logits[b,t,s] = (1/32) q . k   M=2048 N=2048 K=1024, batch B
    mfma_gemm_nt<float><<<dim3(T / 128, T / 128, B), 256, 0, stream>>>(
        qbf, kv, out_w, nullptr, D, B * D, B * E, T,
        (long long)D, (long long)E, (long long)T * T, 0.03125f);

    // 4) softmax rows in-place (output 1) + bf16 copy into Pbf
    softmax_kernel<<<dim3(B * T), 256, 0, stream>>>(out_w, Pbf);

    // 5) amid[t,b,d] = P . vt^T      M=2048 N=1024 K=2048, batch B
    mfma_gemm_nt<ushort><<<dim3(D / 128, T / 128, B), 256, 0, stream>>>(
        Pbf, vt, amid, nullptr, T, T, T, B * D,
        (long long)T * T, (long long)D * T, (long long)D, 1.0f);

    // 6) out = amid . Wout^T + b_out  M=8192 N=1024 K=1024
    mfma_gemm_nt<float><<<dim3(D / 128, M1 / 128, 1), 256, 0, stream>>>(
        amid, wobf, out_attn, b_out, D, D, D, D, 0, 0, 0, 1.0f);
}